// Round 2
// baseline (151.301 us; speedup 1.0000x reference)
//
#include <hip/hip_runtime.h>
#include <hip/hip_bf16.h>
#include <stdint.h>

#define NN 8192
#define INF 128
#define OUTF 64
#define ALPHA 0.2f

typedef __attribute__((ext_vector_type(8))) short s16x8;
typedef __attribute__((ext_vector_type(4))) float f32x4;
typedef __attribute__((ext_vector_type(4))) int i32x4;

__device__ __forceinline__ unsigned short f2bf(float f) {
    union { float f; unsigned int u; } v; v.f = f;
    unsigned int r = v.u + 0x7fffu + ((v.u >> 16) & 1u);
    return (unsigned short)(r >> 16);
}
__device__ __forceinline__ float bf2f(unsigned short b) {
    union { unsigned int u; float f; } v; v.u = ((unsigned int)b) << 16;
    return v.f;
}

// Kernel 1: Wh = h@W -> Wh1, Wh2 (f32) and WhbT (bf16, transposed [64][8192])
__global__ void prep_kernel(const float* __restrict__ h, const float* __restrict__ W,
                            const float* __restrict__ a,
                            float* __restrict__ Wh1, float* __restrict__ Wh2,
                            unsigned short* __restrict__ WhbT) {
    __shared__ float ldsW[INF * OUTF];   // 32 KB
    int t = threadIdx.x;
    for (int idx = t; idx < INF * OUTF; idx += 256) ldsW[idx] = W[idx];
    __syncthreads();
    int r = blockIdx.x * 4 + (t >> 6);   // one row per wave
    int c = t & 63;
    const float4* h4 = reinterpret_cast<const float4*>(h + (size_t)r * INF);
    float dot = 0.f;
#pragma unroll
    for (int kk = 0; kk < INF / 4; ++kk) {
        float4 hv = h4[kk];
        dot += hv.x * ldsW[(4 * kk + 0) * OUTF + c];
        dot += hv.y * ldsW[(4 * kk + 1) * OUTF + c];
        dot += hv.z * ldsW[(4 * kk + 2) * OUTF + c];
        dot += hv.w * ldsW[(4 * kk + 3) * OUTF + c];
    }
    WhbT[(size_t)c * NN + r] = f2bf(dot);
    float v1 = dot * a[c];
    float v2 = dot * a[OUTF + c];
#pragma unroll
    for (int off = 32; off >= 1; off >>= 1) {
        v1 += __shfl_xor(v1, off, 64);
        v2 += __shfl_xor(v2, off, 64);
    }
    if (c == 0) { Wh1[r] = v1; Wh2[r] = v2; }
}

// Kernel 1b: global max of Wh2
__global__ void max_kernel(const float* __restrict__ Wh2, float* __restrict__ maxOut) {
    __shared__ float red[4];
    int t = threadIdx.x;
    float m = -3.4e38f;
    for (int i = t; i < NN; i += 256) m = fmaxf(m, Wh2[i]);
#pragma unroll
    for (int off = 32; off >= 1; off >>= 1) m = fmaxf(m, __shfl_xor(m, off, 64));
    if ((t & 63) == 0) red[t >> 6] = m;
    __syncthreads();
    if (t == 0) maxOut[0] = fmaxf(fmaxf(red[0], red[1]), fmaxf(red[2], red[3]));
}

// Kernel 2: fused masked-softmax attention + PV via MFMA.
// Block: 16 rows; 8 waves each own a 1024-wide j chunk. No online rescale:
// M_i = lrelu(Wh1[i] + max Wh2) is a global per-row upper bound, partials add.
__launch_bounds__(512, 4)
__global__ void attn_kernel(const int* __restrict__ adj,
                            const float* __restrict__ Wh1, const float* __restrict__ Wh2,
                            const unsigned short* __restrict__ WhbT,
                            const float* __restrict__ maxW2,
                            float* __restrict__ out) {
    __shared__ float lds_acc[16][OUTF];
    __shared__ float lds_s[16];
    int tid = threadIdx.x;
    for (int i = tid; i < 16 * OUTF; i += 512) ((float*)lds_acc)[i] = 0.f;
    if (tid < 16) lds_s[tid] = 0.f;
    __syncthreads();

    const int w = tid >> 6;       // wave 0..7 -> j chunk
    const int l = tid & 63;       // lane
    const int il = l & 15;        // A-row / B-col within tile
    const int ks = l >> 4;        // k-slot 0..3 (8 k's each)
    const int rowbase = blockIdx.x * 16;
    const int i = rowbase + il;

    const float wh1 = Wh1[i];
    float M = wh1 + maxW2[0];
    M = fmaxf(M, ALPHA * M);      // lrelu of upper bound == upper bound of lrelu

    f32x4 acc[4] = {{0,0,0,0},{0,0,0,0},{0,0,0,0},{0,0,0,0}};
    float s = 0.f;

    const size_t adjRow = (size_t)i * NN;
    const int jbeg = w * (NN / 8);
    const int jend = jbeg + (NN / 8);
    for (int jb = jbeg; jb < jend; jb += 32) {
        const int j0 = jb + ks * 8;
        i32x4 a0 = __builtin_nontemporal_load(reinterpret_cast<const i32x4*>(adj + adjRow + j0));
        i32x4 a1 = __builtin_nontemporal_load(reinterpret_cast<const i32x4*>(adj + adjRow + j0 + 4));
        float4 w2a = *reinterpret_cast<const float4*>(Wh2 + j0);
        float4 w2b = *reinterpret_cast<const float4*>(Wh2 + j0 + 4);
        float wv[8] = {w2a.x, w2a.y, w2a.z, w2a.w, w2b.x, w2b.y, w2b.z, w2b.w};
        int   av[8] = {a0.x, a0.y, a0.z, a0.w, a1.x, a1.y, a1.z, a1.w};
        s16x8 afrag;
#pragma unroll
        for (int b = 0; b < 8; ++b) {
            float x = wh1 + wv[b];
            x = fmaxf(x, ALPHA * x);          // leaky relu
            float pe = __expf(x - M);         // <= 1, no overflow
            pe = av[b] ? pe : 0.f;            // adjacency mask
            unsigned short pb = f2bf(pe);
            afrag[b] = (short)pb;
            s += bf2f(pb);                    // denom matches bf16-rounded numerator
        }
#pragma unroll
        for (int ct = 0; ct < 4; ++ct) {
            s16x8 bfrag = *reinterpret_cast<const s16x8*>(WhbT + (size_t)(ct * 16 + il) * NN + j0);
            acc[ct] = __builtin_amdgcn_mfma_f32_16x16x32_bf16(afrag, bfrag, acc[ct], 0, 0, 0);
        }
    }

    // reduce s across the 4 k-slot lanes of each row
    s += __shfl_xor(s, 16, 64);
    s += __shfl_xor(s, 32, 64);
    if (l < 16) atomicAdd(&lds_s[il], s);
    // D layout: row = 4*ks + r, col = ct*16 + il  (verified C/D mapping)
#pragma unroll
    for (int ct = 0; ct < 4; ++ct)
#pragma unroll
        for (int r = 0; r < 4; ++r)
            atomicAdd(&lds_acc[ks * 4 + r][ct * 16 + il], acc[ct][r]);
    __syncthreads();

    for (int idx = tid; idx < 16 * OUTF; idx += 512) {
        int row = idx >> 6, col = idx & 63;
        float ss = lds_s[row];
        float v = lds_acc[row][col];
        float q = (ss > 0.f) ? v / ss : 0.f;
        out[(size_t)(rowbase + row) * OUTF + col] = (q > 0.f) ? q : (__expf(q) - 1.f);
    }
}

extern "C" void kernel_launch(void* const* d_in, const int* in_sizes, int n_in,
                              void* d_out, int out_size, void* d_ws, size_t ws_size,
                              hipStream_t stream) {
    const float* h   = (const float*)d_in[0];
    const int*   adj = (const int*)d_in[1];
    const float* W   = (const float*)d_in[2];
    const float* a   = (const float*)d_in[3];
    float* out = (float*)d_out;

    char* ws = (char*)d_ws;
    float* Wh1 = (float*)(ws);                         // 32 KB
    float* Wh2 = (float*)(ws + 32 * 1024);             // 32 KB
    unsigned short* WhbT = (unsigned short*)(ws + 64 * 1024);   // 1 MB
    float* maxW2 = (float*)(ws + 64 * 1024 + 1024 * 1024);      // 4 B

    hipLaunchKernelGGL(prep_kernel, dim3(NN / 4), dim3(256), 0, stream, h, W, a, Wh1, Wh2, WhbT);
    hipLaunchKernelGGL(max_kernel, dim3(1), dim3(256), 0, stream, Wh2, maxW2);
    hipLaunchKernelGGL(attn_kernel, dim3(NN / 16), dim3(512), 0, stream, adj, Wh1, Wh2, WhbT, maxW2, out);
}

// Round 3
// 104.043 us; speedup vs baseline: 1.4542x; 1.4542x over previous
//
#include <hip/hip_runtime.h>
#include <hip/hip_bf16.h>
#include <stdint.h>

#define NN 8192
#define INF 128
#define OUTF 64
#define ALPHA 0.2f
#define RB 128      // rows per attn block
#define JB 1024     // j-range per attn block
#define JPH 256     // j per staged phase

typedef __attribute__((ext_vector_type(8))) short s16x8;
typedef __attribute__((ext_vector_type(4))) float f32x4;
typedef __attribute__((ext_vector_type(4))) int i32x4;

typedef __attribute__((address_space(1))) const void ga_cv;
typedef __attribute__((address_space(3))) void lds_v;

__device__ __forceinline__ unsigned short f2bf(float f) {
    union { float f; unsigned int u; } v; v.f = f;
    unsigned int r = v.u + 0x7fffu + ((v.u >> 16) & 1u);
    return (unsigned short)(r >> 16);
}
__device__ __forceinline__ float bf2f(unsigned short b) {
    union { unsigned int u; float f; } v; v.u = ((unsigned int)b) << 16;
    return v.f;
}

// Kernel 1: Wh = h@W -> Wh1, Wh2 (f32) and WhbT (bf16, transposed [64][8192])
__global__ void prep_kernel(const float* __restrict__ h, const float* __restrict__ W,
                            const float* __restrict__ a,
                            float* __restrict__ Wh1, float* __restrict__ Wh2,
                            unsigned short* __restrict__ WhbT) {
    __shared__ float ldsW[INF * OUTF];
    int t = threadIdx.x;
    for (int idx = t; idx < INF * OUTF; idx += 256) ldsW[idx] = W[idx];
    __syncthreads();
    int r = blockIdx.x * 4 + (t >> 6);
    int c = t & 63;
    const float4* h4 = reinterpret_cast<const float4*>(h + (size_t)r * INF);
    float dot = 0.f;
#pragma unroll
    for (int kk = 0; kk < INF / 4; ++kk) {
        float4 hv = h4[kk];
        dot += hv.x * ldsW[(4 * kk + 0) * OUTF + c];
        dot += hv.y * ldsW[(4 * kk + 1) * OUTF + c];
        dot += hv.z * ldsW[(4 * kk + 2) * OUTF + c];
        dot += hv.w * ldsW[(4 * kk + 3) * OUTF + c];
    }
    WhbT[(size_t)c * NN + r] = f2bf(dot);
    float v1 = dot * a[c];
    float v2 = dot * a[OUTF + c];
#pragma unroll
    for (int off = 32; off >= 1; off >>= 1) {
        v1 += __shfl_xor(v1, off, 64);
        v2 += __shfl_xor(v2, off, 64);
    }
    if (c == 0) { Wh1[r] = v1; Wh2[r] = v2; }
}

__global__ void max_kernel(const float* __restrict__ Wh2, float* __restrict__ maxOut) {
    __shared__ float red[4];
    int t = threadIdx.x;
    float m = -3.4e38f;
    for (int i = t; i < NN; i += 256) m = fmaxf(m, Wh2[i]);
#pragma unroll
    for (int off = 32; off >= 1; off >>= 1) m = fmaxf(m, __shfl_xor(m, off, 64));
    if ((t & 63) == 0) red[t >> 6] = m;
    __syncthreads();
    if (t == 0) maxOut[0] = fmaxf(fmaxf(red[0], red[1]), fmaxf(red[2], red[3]));
}

__global__ void zero_kernel(float4* __restrict__ p, int n4) {
    int t = blockIdx.x * blockDim.x + threadIdx.x;
    if (t < n4) p[t] = float4{0.f, 0.f, 0.f, 0.f};
}

// Kernel 2: fused masked-softmax attention + PV via MFMA.
// Block: 128 rows x 1024 j. 8 waves = 8 MFMA row-tiles sharing one LDS-staged
// B-panel (64x256 bf16 per phase, XOR-swizzled via pre-swizzled global src).
// Partials (4 j-groups... 8 j-groups) combine by global atomicAdd: no max
// tracking needed since M_i = lrelu(Wh1[i]+max Wh2) bounds every score.
__launch_bounds__(512, 4)
__global__ void attn_kernel(const int* __restrict__ adj,
                            const float* __restrict__ Wh1, const float* __restrict__ Wh2,
                            const unsigned short* __restrict__ WhbT,
                            const float* __restrict__ maxW2,
                            float* __restrict__ accG, float* __restrict__ sG) {
    __shared__ unsigned short Bpanel[2][64 * JPH];   // 2 x 32KB
    const int tid = threadIdx.x;
    const int w = tid >> 6;       // wave -> row tile
    const int l = tid & 63;
    const int il = l & 15;
    const int ks = l >> 4;
    const int g = blockIdx.x >> 3;
    const int q = blockIdx.x & 7;     // j-group; same-q blocks share WhbT panel
    const int rowbase = g * RB + w * 16;
    const int i = rowbase + il;
    const int jbase = q * JB;

    const float wh1 = Wh1[i];
    float M = wh1 + maxW2[0];
    M = fmaxf(M, ALPHA * M);

    // staging: wave w stages panel rows c = w*8 .. w*8+7 (4 calls x 2 rows)
    const int c_lo = w * 8 + (l >> 5);      // + 2*k per call
    const int jst = (l & 31) * 8;           // storage-element offset in row

#define STAGE(ph) { \
    unsigned short* dst = &Bpanel[(ph) & 1][w * 2048]; \
    _Pragma("unroll") \
    for (int k = 0; k < 4; ++k) { \
        int c = c_lo + 2 * k; \
        int jl = jst ^ ((c & 7) * 8); \
        const unsigned short* src = WhbT + (size_t)c * NN + jbase + (ph) * JPH + jl; \
        __builtin_amdgcn_global_load_lds((ga_cv*)src, (lds_v*)(dst + k * 512), 16, 0, 0); \
    } }

    f32x4 acc[4] = {{0,0,0,0},{0,0,0,0},{0,0,0,0},{0,0,0,0}};
    float s = 0.f;
    const size_t adjRow = (size_t)i * NN;
    const int swzmask = (il & 7) * 8;       // element-XOR for B reads (c&7 == il&7)

    STAGE(0);
    for (int ph = 0; ph < JB / JPH; ++ph) {
        __syncthreads();                     // staged panel visible (drains vmcnt)
        if (ph < JB / JPH - 1) STAGE(ph + 1);
        const unsigned short* bp = &Bpanel[ph & 1][il * JPH];
#pragma unroll
        for (int ks8 = 0; ks8 < JPH / 32; ++ks8) {
            const int j0 = jbase + ph * JPH + ks8 * 32 + ks * 8;
            i32x4 a0 = __builtin_nontemporal_load(reinterpret_cast<const i32x4*>(adj + adjRow + j0));
            i32x4 a1 = __builtin_nontemporal_load(reinterpret_cast<const i32x4*>(adj + adjRow + j0 + 4));
            float4 w2a = *reinterpret_cast<const float4*>(Wh2 + j0);
            float4 w2b = *reinterpret_cast<const float4*>(Wh2 + j0 + 4);
            float wv[8] = {w2a.x, w2a.y, w2a.z, w2a.w, w2b.x, w2b.y, w2b.z, w2b.w};
            int   av[8] = {a0.x, a0.y, a0.z, a0.w, a1.x, a1.y, a1.z, a1.w};
            s16x8 afrag;
#pragma unroll
            for (int b = 0; b < 8; ++b) {
                float x = wh1 + wv[b];
                x = fmaxf(x, ALPHA * x);
                float pe = __expf(x - M);
                pe = av[b] ? pe : 0.f;
                unsigned short pb = f2bf(pe);
                afrag[b] = (short)pb;
                s += bf2f(pb);
            }
            const int off_e = (ks8 * 32 + ks * 8) ^ swzmask;
#pragma unroll
            for (int ct = 0; ct < 4; ++ct) {
                s16x8 bfrag = *reinterpret_cast<const s16x8*>(bp + ct * 16 * JPH + off_e);
                acc[ct] = __builtin_amdgcn_mfma_f32_16x16x32_bf16(afrag, bfrag, acc[ct], 0, 0, 0);
            }
        }
    }

    // combine partials across j-groups
    s += __shfl_xor(s, 16, 64);
    s += __shfl_xor(s, 32, 64);
    if (l < 16) atomicAdd(&sG[i], s);
#pragma unroll
    for (int ct = 0; ct < 4; ++ct)
#pragma unroll
        for (int r = 0; r < 4; ++r)
            atomicAdd(&accG[(size_t)(rowbase + ks * 4 + r) * OUTF + ct * 16 + il], acc[ct][r]);
}

__global__ void finalize_kernel(const float* __restrict__ accG, const float* __restrict__ sG,
                                float* __restrict__ out) {
    int t4 = blockIdx.x * blockDim.x + threadIdx.x;   // float4 index
    if (t4 >= NN * OUTF / 4) return;
    int row = t4 >> 4;
    float ss = sG[row];
    float4 v = reinterpret_cast<const float4*>(accG)[t4];
    float inv = (ss > 0.f) ? 1.f / ss : 0.f;
    float r[4] = {v.x * inv, v.y * inv, v.z * inv, v.w * inv};
#pragma unroll
    for (int k = 0; k < 4; ++k) r[k] = (r[k] > 0.f) ? r[k] : (__expf(r[k]) - 1.f);
    reinterpret_cast<float4*>(out)[t4] = float4{r[0], r[1], r[2], r[3]};
}

extern "C" void kernel_launch(void* const* d_in, const int* in_sizes, int n_in,
                              void* d_out, int out_size, void* d_ws, size_t ws_size,
                              hipStream_t stream) {
    const float* h   = (const float*)d_in[0];
    const int*   adj = (const int*)d_in[1];
    const float* W   = (const float*)d_in[2];
    const float* a   = (const float*)d_in[3];
    float* out = (float*)d_out;

    char* ws = (char*)d_ws;
    float* Wh1 = (float*)(ws);                                   // 32 KB
    float* Wh2 = (float*)(ws + 32 * 1024);                       // 32 KB
    unsigned short* WhbT = (unsigned short*)(ws + 64 * 1024);    // 1 MB
    float* maxW2 = (float*)(ws + 64 * 1024 + 1024 * 1024);       // 4 B
    float* accG = (float*)(ws + 2 * 1024 * 1024);                // 2 MB
    float* sG   = (float*)(ws + 4 * 1024 * 1024 + 128 * 1024);   // 32 KB (contiguous after accG pad)

    // zero the accumulators (acc 524288 + gap... zero exactly the two regions)
    hipLaunchKernelGGL(zero_kernel, dim3((NN * OUTF / 4 + 255) / 256), dim3(256), 0, stream,
                       (float4*)accG, NN * OUTF / 4);
    hipLaunchKernelGGL(zero_kernel, dim3((NN / 4 + 255) / 256), dim3(256), 0, stream,
                       (float4*)sG, NN / 4);
    hipLaunchKernelGGL(prep_kernel, dim3(NN / 4), dim3(256), 0, stream, h, W, a, Wh1, Wh2, WhbT);
    hipLaunchKernelGGL(max_kernel, dim3(1), dim3(256), 0, stream, Wh2, maxW2);
    hipLaunchKernelGGL(attn_kernel, dim3((NN / RB) * (NN / JB)), dim3(512), 0, stream,
                       adj, Wh1, Wh2, WhbT, maxW2, accG, sG);
    hipLaunchKernelGGL(finalize_kernel, dim3(NN * OUTF / 4 / 256), dim3(256), 0, stream,
                       accG, sG, out);
}